// Round 3
// baseline (252.814 us; speedup 1.0000x reference)
//
#include <hip/hip_runtime.h>
#include <math.h>

#define DD 768
#define DD4 192
#define KK 16
#define EPSV 1e-5f

// DPP-based partial reduction: after xor1+xor2 (quad sums) + row_half_mirror
// (lane^7, closed within each 8-lane group), ALL lanes of each 8-group hold
// the 8-lane sum. Symmetric permutes -> no shift-direction ambiguity.
template <int CTRL>
__device__ __forceinline__ float dpp_add(float v) {
    int t = __builtin_amdgcn_update_dpp(0, __float_as_int(v), CTRL, 0xF, 0xF, true);
    return v + __int_as_float(t);
}
#define DPP_XOR1 0xB1
#define DPP_XOR2 0x4E
#define DPP_HMIR 0x141

__device__ __forceinline__ float red8(float v) {
    v = dpp_add<DPP_XOR1>(v);
    v = dpp_add<DPP_XOR2>(v);
    v = dpp_add<DPP_HMIR>(v);
    return v;   // 8-group sum in every lane of the group
}

// One wave = 2 rows/iter, x-prefetch pipeline. DPP reduce to 8 groups ->
// 9 ds_write_b128 -> 8 ds_read_b32 transpose. LDS = 49152 + 5120 = 54272 B
// (= 106*512) -> 3 blocks/CU, 12 waves/CU.
__global__ __launch_bounds__(256, 3)
void sln_kernel(const float* __restrict__ x,
                const float* __restrict__ weights,
                const float* __restrict__ biases,
                const float* __restrict__ centroids,
                float* __restrict__ out,
                float* __restrict__ bkt,
                int nrows)
{
    __shared__ float cs[KK * DD];        // 48 KB centroids
    __shared__ float scr[4][8][40];      // 5 KB per-wave transpose scratch

    const int tid  = threadIdx.x;
    const int lane = tid & 63;
    const int wave = tid >> 6;

    // stage centroids (coalesced float4)
    {
        const float4* c4 = (const float4*)centroids;
        float4* cs4w = (float4*)cs;
        for (int i = tid; i < KK * DD4; i += 256) cs4w[i] = c4[i];
    }
    __syncthreads();

    // c2[k] via block-wide partials in scr (reused as flat scratch, 1280 floats)
    float* flat = &scr[0][0][0];
    {
        int k = tid >> 4, t = tid & 15;
        float p = 0.f;
        #pragma unroll
        for (int j = 0; j < DD / 16; ++j) {
            float v = cs[k * DD + t + 16 * j];
            p += v * v;
        }
        flat[tid] = p;
    }
    __syncthreads();
    if (tid < KK) {
        float sacc = 0.f;
        #pragma unroll
        for (int i = 0; i < 16; ++i) sacc += flat[tid * 16 + i];
        flat[256 + tid] = sacc;
    }
    __syncthreads();
    const float c2reg = flat[256 + (lane & 15)];   // each lane: c2[lane&15]
    __syncthreads();                               // scr reused below

    const float4* cs4 = (const float4*)cs;
    const int npairs = nrows >> 1;
    const int pstride = gridDim.x * 4;
    int pair = blockIdx.x * 4 + wave;
    bool valid = pair < npairs;

    float4 a0, a1, a2, b0, b1, b2;
    if (valid) {
        const float4* xr0 = (const float4*)(x + (size_t)(2 * pair) * DD);
        const float4* xr1 = (const float4*)(x + (size_t)(2 * pair + 1) * DD);
        a0 = xr0[lane]; a1 = xr0[lane + 64]; a2 = xr0[lane + 128];
        b0 = xr1[lane]; b1 = xr1[lane + 64]; b2 = xr1[lane + 128];
    }

    while (valid) {
        const int r0 = 2 * pair, r1 = r0 + 1;
        const int npair = pair + pstride;
        const bool nvalid = npair < npairs;

        // prefetch next pair's x (covered by the dot-compute below)
        float4 na0, na1, na2, nb0, nb1, nb2;
        if (nvalid) {
            const float4* xr0 = (const float4*)(x + (size_t)(2 * npair) * DD);
            const float4* xr1 = (const float4*)(x + (size_t)(2 * npair + 1) * DD);
            na0 = xr0[lane]; na1 = xr0[lane + 64]; na2 = xr0[lane + 128];
            nb0 = xr1[lane]; nb1 = xr1[lane + 64]; nb2 = xr1[lane + 128];
        }

        // per-lane partials
        float s0 = a0.x+a0.y+a0.z+a0.w + a1.x+a1.y+a1.z+a1.w + a2.x+a2.y+a2.z+a2.w;
        float ss0 = a0.x*a0.x+a0.y*a0.y+a0.z*a0.z+a0.w*a0.w
                  + a1.x*a1.x+a1.y*a1.y+a1.z*a1.z+a1.w*a1.w
                  + a2.x*a2.x+a2.y*a2.y+a2.z*a2.z+a2.w*a2.w;
        float s1 = b0.x+b0.y+b0.z+b0.w + b1.x+b1.y+b1.z+b1.w + b2.x+b2.y+b2.z+b2.w;
        float ss1 = b0.x*b0.x+b0.y*b0.y+b0.z*b0.z+b0.w*b0.w
                  + b1.x*b1.x+b1.y*b1.y+b1.z*b1.z+b1.w*b1.w
                  + b2.x*b2.x+b2.y*b2.y+b2.z*b2.z+b2.w*b2.w;

        float d0[KK], d1[KK];
        #pragma unroll
        for (int k = 0; k < KK; ++k) {
            float4 c0 = cs4[k * DD4 + lane];
            float4 c1 = cs4[k * DD4 + lane + 64];
            float4 c2 = cs4[k * DD4 + lane + 128];
            d0[k] = a0.x*c0.x + a0.y*c0.y + a0.z*c0.z + a0.w*c0.w
                  + a1.x*c1.x + a1.y*c1.y + a1.z*c1.z + a1.w*c1.w
                  + a2.x*c2.x + a2.y*c2.y + a2.z*c2.z + a2.w*c2.w;
            d1[k] = b0.x*c0.x + b0.y*c0.y + b0.z*c0.z + b0.w*c0.w
                  + b1.x*c1.x + b1.y*c1.y + b1.z*c1.z + b1.w*c1.w
                  + b2.x*c2.x + b2.y*c2.y + b2.z*c2.z + b2.w*c2.w;
        }

        // DPP reduce all 36 values to 8-lane-group sums (VALU pipe, no LDS)
        #pragma unroll
        for (int k = 0; k < KK; ++k) { d0[k] = red8(d0[k]); d1[k] = red8(d1[k]); }
        s0 = red8(s0); ss0 = red8(ss0); s1 = red8(s1); ss1 = red8(ss1);

        // group leaders write 36 values (9 x ds_write_b128)
        if ((lane & 7) == 0) {
            int g = lane >> 3;
            float4* p4 = (float4*)&scr[wave][g][0];
            p4[0] = make_float4(d0[0],  d0[1],  d0[2],  d0[3]);
            p4[1] = make_float4(d0[4],  d0[5],  d0[6],  d0[7]);
            p4[2] = make_float4(d0[8],  d0[9],  d0[10], d0[11]);
            p4[3] = make_float4(d0[12], d0[13], d0[14], d0[15]);
            p4[4] = make_float4(s0, ss0, d1[0], d1[1]);
            p4[5] = make_float4(d1[2],  d1[3],  d1[4],  d1[5]);
            p4[6] = make_float4(d1[6],  d1[7],  d1[8],  d1[9]);
            p4[7] = make_float4(d1[10], d1[11], d1[12], d1[13]);
            p4[8] = make_float4(d1[14], d1[15], s1, ss1);
        }
        __asm__ volatile("" ::: "memory");

        // transpose: lanes 0..17 -> row0 slots, lanes 32..49 -> row1 slots
        float T = 0.f;
        if (lane < 18 || (lane >= 32 && lane < 50)) {
            int slot = (lane < 32) ? lane : (lane - 14);
            float t0 = 0.f, t1 = 0.f, t2 = 0.f, t3 = 0.f;
            t0 = scr[wave][0][slot] + scr[wave][4][slot];
            t1 = scr[wave][1][slot] + scr[wave][5][slot];
            t2 = scr[wave][2][slot] + scr[wave][6][slot];
            t3 = scr[wave][3][slot] + scr[wave][7][slot];
            T = (t0 + t1) + (t2 + t3);
        }
        __asm__ volatile("" ::: "memory");

        // broadcast row sums (readlane -> uniform)
        const float sA  = __int_as_float(__builtin_amdgcn_readlane(__float_as_int(T), 16));
        const float ssA = __int_as_float(__builtin_amdgcn_readlane(__float_as_int(T), 17));
        const float sB  = __int_as_float(__builtin_amdgcn_readlane(__float_as_int(T), 48));
        const float ssB = __int_as_float(__builtin_amdgcn_readlane(__float_as_int(T), 49));

        // argmin in 16-lane groups (lanes 0..15 row0, 32..47 row1)
        const int v = lane & 15;
        const float ssSel = (lane & 32) ? ssB : ssA;
        float sq = (ssSel - 2.f * T) + c2reg;
        int idx = v;
        #pragma unroll
        for (int m = 1; m < 16; m <<= 1) {
            float osq = __shfl_xor(sq, m);
            int   oidx = __shfl_xor(idx, m);
            bool take = (osq < sq) || (osq == sq && oidx < idx);
            sq  = take ? osq  : sq;
            idx = take ? oidx : idx;
        }
        const int bk0 = __builtin_amdgcn_readlane(idx, 0);
        const int bk1 = __builtin_amdgcn_readlane(idx, 32);

        const float mean0 = sA * (1.f / DD);
        const float mean1 = sB * (1.f / DD);
        const float rstd0 = 1.f / sqrtf(ssA * (1.f / DD) - mean0 * mean0 + EPSV);
        const float rstd1 = 1.f / sqrtf(ssB * (1.f / DD) - mean1 * mean1 + EPSV);

        if (lane == 0) {
            bkt[r0] = (float)bk0;
            bkt[r1] = (float)bk1;
        }

        const float4* w0 = (const float4*)(weights + (size_t)bk0 * DD);
        const float4* g0 = (const float4*)(biases  + (size_t)bk0 * DD);
        const float4* w1 = (const float4*)(weights + (size_t)bk1 * DD);
        const float4* g1 = (const float4*)(biases  + (size_t)bk1 * DD);
        float4* o0 = (float4*)(out + (size_t)r0 * DD);
        float4* o1 = (float4*)(out + (size_t)r1 * DD);

        #pragma unroll
        for (int j = 0; j < 3; ++j) {
            float4 xv = (j == 0) ? a0 : (j == 1) ? a1 : a2;
            float4 wv = w0[lane + 64 * j];
            float4 bv = g0[lane + 64 * j];
            float4 o;
            o.x = (xv.x - mean0) * rstd0 * wv.x + bv.x;
            o.y = (xv.y - mean0) * rstd0 * wv.y + bv.y;
            o.z = (xv.z - mean0) * rstd0 * wv.z + bv.z;
            o.w = (xv.w - mean0) * rstd0 * wv.w + bv.w;
            o0[lane + 64 * j] = o;
        }
        #pragma unroll
        for (int j = 0; j < 3; ++j) {
            float4 xv = (j == 0) ? b0 : (j == 1) ? b1 : b2;
            float4 wv = w1[lane + 64 * j];
            float4 bv = g1[lane + 64 * j];
            float4 o;
            o.x = (xv.x - mean1) * rstd1 * wv.x + bv.x;
            o.y = (xv.y - mean1) * rstd1 * wv.y + bv.y;
            o.z = (xv.z - mean1) * rstd1 * wv.z + bv.z;
            o.w = (xv.w - mean1) * rstd1 * wv.w + bv.w;
            o1[lane + 64 * j] = o;
        }

        a0 = na0; a1 = na1; a2 = na2;
        b0 = nb0; b1 = nb1; b2 = nb2;
        pair = npair; valid = nvalid;
    }
}

extern "C" void kernel_launch(void* const* d_in, const int* in_sizes, int n_in,
                              void* d_out, int out_size, void* d_ws, size_t ws_size,
                              hipStream_t stream) {
    const float* x         = (const float*)d_in[0];
    const float* weights   = (const float*)d_in[1];
    const float* biases    = (const float*)d_in[2];
    const float* centroids = (const float*)d_in[3];

    const int nrows = in_sizes[0] / DD;   // 32768

    float* out = (float*)d_out;
    float* bkt = out + (size_t)nrows * DD;

    dim3 grid(768), block(256);   // persistent: 3 blocks/CU x 256 CUs
    hipLaunchKernelGGL(sln_kernel, grid, block, 0, stream,
                       x, weights, biases, centroids, out, bkt, nrows);
}

// Round 5
// 199.221 us; speedup vs baseline: 1.2690x; 1.2690x over previous
//
#include <hip/hip_runtime.h>
#include <math.h>

#define DD 768
#define DD4 192
#define KK 16
#define EPSV 1e-5f

// DPP 8-lane-group reduction: xor1 (quad_perm 0xB1), xor2 (0x4E),
// row_half_mirror (0x141, lane^7 within 8-group). All symmetric -> after 3
// steps every lane of each 8-lane group holds the group sum. VALU pipe only.
template <int CTRL>
__device__ __forceinline__ float dpp_add(float v) {
    int t = __builtin_amdgcn_update_dpp(0, __float_as_int(v), CTRL, 0xF, 0xF, true);
    return v + __int_as_float(t);
}
#define DPP_XOR1 0xB1
#define DPP_XOR2 0x4E
#define DPP_HMIR 0x141

__device__ __forceinline__ float red8(float v) {
    v = dpp_add<DPP_XOR1>(v);
    v = dpp_add<DPP_XOR2>(v);
    v = dpp_add<DPP_HMIR>(v);
    return v;
}

// native vector type for nontemporal builtins (HIP_vector_type is rejected)
typedef float nfloat4 __attribute__((ext_vector_type(4)));

__device__ __forceinline__ float4 ntload4(const float4* p) {
    nfloat4 v = __builtin_nontemporal_load((const nfloat4*)p);
    return make_float4(v.x, v.y, v.z, v.w);
}
__device__ __forceinline__ void ntstore4(float4* p, float4 v) {
    nfloat4 t = {v.x, v.y, v.z, v.w};
    __builtin_nontemporal_store(t, (nfloat4*)p);
}

// One wave = 2 rows/iter. R2 schedule (grid 2048, stride 8192 pairs — known
// good HBM traffic profile). DPP reduce -> 9x ds_write_b128 -> transpose.
// LDS = 49152 + 5120 = 54272 B -> 3 blocks/CU, 12 waves/CU.
__global__ __launch_bounds__(256, 3)
void sln_kernel(const float* __restrict__ x,
                const float* __restrict__ weights,
                const float* __restrict__ biases,
                const float* __restrict__ centroids,
                float* __restrict__ out,
                float* __restrict__ bkt,
                int nrows)
{
    __shared__ float cs[KK * DD];        // 48 KB centroids
    __shared__ float scr[4][8][40];      // 5 KB per-wave transpose scratch

    const int tid  = threadIdx.x;
    const int lane = tid & 63;
    const int wave = tid >> 6;

    // stage centroids (coalesced float4)
    {
        const float4* c4 = (const float4*)centroids;
        float4* cs4w = (float4*)cs;
        for (int i = tid; i < KK * DD4; i += 256) cs4w[i] = c4[i];
    }
    __syncthreads();

    // c2[k] via block-wide partials in scr (reused as flat scratch)
    float* flat = &scr[0][0][0];
    {
        int k = tid >> 4, t = tid & 15;
        float p = 0.f;
        #pragma unroll
        for (int j = 0; j < DD / 16; ++j) {
            float v = cs[k * DD + t + 16 * j];
            p += v * v;
        }
        flat[tid] = p;
    }
    __syncthreads();
    if (tid < KK) {
        float sacc = 0.f;
        #pragma unroll
        for (int i = 0; i < 16; ++i) sacc += flat[tid * 16 + i];
        flat[256 + tid] = sacc;
    }
    __syncthreads();
    const float c2reg = flat[256 + (lane & 15)];
    __syncthreads();                     // scr reused below

    const float4* cs4 = (const float4*)cs;
    const int gw = blockIdx.x * 4 + wave;
    const int wstride = gridDim.x * 4;

    for (int pair = gw; pair * 2 < nrows; pair += wstride) {
        const int r0 = pair * 2;
        const int r1 = r0 + 1;

        const float4* xr0 = (const float4*)(x + (size_t)r0 * DD);
        const float4* xr1 = (const float4*)(x + (size_t)r1 * DD);
        float4 a0 = ntload4(xr0 + lane);
        float4 a1 = ntload4(xr0 + lane + 64);
        float4 a2 = ntload4(xr0 + lane + 128);
        float4 b0 = ntload4(xr1 + lane);
        float4 b1 = ntload4(xr1 + lane + 64);
        float4 b2 = ntload4(xr1 + lane + 128);

        // per-lane partials
        float s0 = a0.x+a0.y+a0.z+a0.w + a1.x+a1.y+a1.z+a1.w + a2.x+a2.y+a2.z+a2.w;
        float ss0 = a0.x*a0.x+a0.y*a0.y+a0.z*a0.z+a0.w*a0.w
                  + a1.x*a1.x+a1.y*a1.y+a1.z*a1.z+a1.w*a1.w
                  + a2.x*a2.x+a2.y*a2.y+a2.z*a2.z+a2.w*a2.w;
        float s1 = b0.x+b0.y+b0.z+b0.w + b1.x+b1.y+b1.z+b1.w + b2.x+b2.y+b2.z+b2.w;
        float ss1 = b0.x*b0.x+b0.y*b0.y+b0.z*b0.z+b0.w*b0.w
                  + b1.x*b1.x+b1.y*b1.y+b1.z*b1.z+b1.w*b1.w
                  + b2.x*b2.x+b2.y*b2.y+b2.z*b2.z+b2.w*b2.w;

        float d0[KK], d1[KK];
        #pragma unroll
        for (int k = 0; k < KK; ++k) {
            float4 c0 = cs4[k * DD4 + lane];
            float4 c1 = cs4[k * DD4 + lane + 64];
            float4 c2 = cs4[k * DD4 + lane + 128];
            d0[k] = a0.x*c0.x + a0.y*c0.y + a0.z*c0.z + a0.w*c0.w
                  + a1.x*c1.x + a1.y*c1.y + a1.z*c1.z + a1.w*c1.w
                  + a2.x*c2.x + a2.y*c2.y + a2.z*c2.z + a2.w*c2.w;
            d1[k] = b0.x*c0.x + b0.y*c0.y + b0.z*c0.z + b0.w*c0.w
                  + b1.x*c1.x + b1.y*c1.y + b1.z*c1.z + b1.w*c1.w
                  + b2.x*c2.x + b2.y*c2.y + b2.z*c2.z + b2.w*c2.w;
        }

        // DPP reduce all 36 values to 8-lane-group sums (VALU pipe)
        #pragma unroll
        for (int k = 0; k < KK; ++k) { d0[k] = red8(d0[k]); d1[k] = red8(d1[k]); }
        s0 = red8(s0); ss0 = red8(ss0); s1 = red8(s1); ss1 = red8(ss1);

        // group leaders write 36 values (9 x ds_write_b128)
        if ((lane & 7) == 0) {
            int g = lane >> 3;
            float4* p4 = (float4*)&scr[wave][g][0];
            p4[0] = make_float4(d0[0],  d0[1],  d0[2],  d0[3]);
            p4[1] = make_float4(d0[4],  d0[5],  d0[6],  d0[7]);
            p4[2] = make_float4(d0[8],  d0[9],  d0[10], d0[11]);
            p4[3] = make_float4(d0[12], d0[13], d0[14], d0[15]);
            p4[4] = make_float4(s0, ss0, d1[0], d1[1]);
            p4[5] = make_float4(d1[2],  d1[3],  d1[4],  d1[5]);
            p4[6] = make_float4(d1[6],  d1[7],  d1[8],  d1[9]);
            p4[7] = make_float4(d1[10], d1[11], d1[12], d1[13]);
            p4[8] = make_float4(d1[14], d1[15], s1, ss1);
        }
        __asm__ volatile("" ::: "memory");   // intra-wave LDS RAW: in-order per wave

        // transpose: lanes 0..17 -> row0 slots, lanes 32..49 -> row1 slots
        float T = 0.f;
        if (lane < 18 || (lane >= 32 && lane < 50)) {
            int slot = (lane < 32) ? lane : (lane - 14);
            float t0 = scr[wave][0][slot] + scr[wave][4][slot];
            float t1 = scr[wave][1][slot] + scr[wave][5][slot];
            float t2 = scr[wave][2][slot] + scr[wave][6][slot];
            float t3 = scr[wave][3][slot] + scr[wave][7][slot];
            T = (t0 + t1) + (t2 + t3);
        }
        __asm__ volatile("" ::: "memory");

        // broadcast row sums
        const float sA  = __int_as_float(__builtin_amdgcn_readlane(__float_as_int(T), 16));
        const float ssA = __int_as_float(__builtin_amdgcn_readlane(__float_as_int(T), 17));
        const float sB  = __int_as_float(__builtin_amdgcn_readlane(__float_as_int(T), 48));
        const float ssB = __int_as_float(__builtin_amdgcn_readlane(__float_as_int(T), 49));

        // argmin in 16-lane groups (lanes 0..15 row0, 32..47 row1)
        const int v = lane & 15;
        const float ssSel = (lane & 32) ? ssB : ssA;
        float sq = (ssSel - 2.f * T) + c2reg;
        int idx = v;
        #pragma unroll
        for (int m = 1; m < 16; m <<= 1) {
            float osq = __shfl_xor(sq, m);
            int   oidx = __shfl_xor(idx, m);
            bool take = (osq < sq) || (osq == sq && oidx < idx);
            sq  = take ? osq  : sq;
            idx = take ? oidx : idx;
        }
        const int bk0 = __builtin_amdgcn_readlane(idx, 0);
        const int bk1 = __builtin_amdgcn_readlane(idx, 32);

        const float mean0 = sA * (1.f / DD);
        const float mean1 = sB * (1.f / DD);
        const float rstd0 = 1.f / sqrtf(ssA * (1.f / DD) - mean0 * mean0 + EPSV);
        const float rstd1 = 1.f / sqrtf(ssB * (1.f / DD) - mean1 * mean1 + EPSV);

        if (lane == 0) {
            bkt[r0] = (float)bk0;
            bkt[r1] = (float)bk1;
        }

        const float4* w0 = (const float4*)(weights + (size_t)bk0 * DD);
        const float4* g0 = (const float4*)(biases  + (size_t)bk0 * DD);
        const float4* w1 = (const float4*)(weights + (size_t)bk1 * DD);
        const float4* g1 = (const float4*)(biases  + (size_t)bk1 * DD);
        float4* o0 = (float4*)(out + (size_t)r0 * DD);
        float4* o1 = (float4*)(out + (size_t)r1 * DD);

        #pragma unroll
        for (int j = 0; j < 3; ++j) {
            float4 xv = (j == 0) ? a0 : (j == 1) ? a1 : a2;
            float4 wv = w0[lane + 64 * j];
            float4 bv = g0[lane + 64 * j];
            float4 o;
            o.x = (xv.x - mean0) * rstd0 * wv.x + bv.x;
            o.y = (xv.y - mean0) * rstd0 * wv.y + bv.y;
            o.z = (xv.z - mean0) * rstd0 * wv.z + bv.z;
            o.w = (xv.w - mean0) * rstd0 * wv.w + bv.w;
            ntstore4(o0 + lane + 64 * j, o);
        }
        #pragma unroll
        for (int j = 0; j < 3; ++j) {
            float4 xv = (j == 0) ? b0 : (j == 1) ? b1 : b2;
            float4 wv = w1[lane + 64 * j];
            float4 bv = g1[lane + 64 * j];
            float4 o;
            o.x = (xv.x - mean1) * rstd1 * wv.x + bv.x;
            o.y = (xv.y - mean1) * rstd1 * wv.y + bv.y;
            o.z = (xv.z - mean1) * rstd1 * wv.z + bv.z;
            o.w = (xv.w - mean1) * rstd1 * wv.w + bv.w;
            ntstore4(o1 + lane + 64 * j, o);
        }
    }
}

extern "C" void kernel_launch(void* const* d_in, const int* in_sizes, int n_in,
                              void* d_out, int out_size, void* d_ws, size_t ws_size,
                              hipStream_t stream) {
    const float* x         = (const float*)d_in[0];
    const float* weights   = (const float*)d_in[1];
    const float* biases    = (const float*)d_in[2];
    const float* centroids = (const float*)d_in[3];

    const int nrows = in_sizes[0] / DD;   // 32768

    float* out = (float*)d_out;
    float* bkt = out + (size_t)nrows * DD;

    dim3 grid(2048), block(256);
    hipLaunchKernelGGL(sln_kernel, grid, block, 0, stream,
                       x, weights, biases, centroids, out, bkt, nrows);
}